// Round 10
// baseline (754.854 us; speedup 1.0000x reference)
//
#include <hip/hip_runtime.h>

typedef __attribute__((ext_vector_type(8))) short bf16x8;
typedef __attribute__((ext_vector_type(16))) float f32x16;

namespace {
constexpr int BB   = 64;
constexpr int CC   = 64;
constexpr int HH   = 64;
constexpr int WW   = 64;
constexpr int HW   = HH * WW;   // 4096
constexpr int CHW  = CC * HW;   // 262144
constexpr int NTOT = BB * CHW;  // 16777216
}

__device__ __forceinline__ ushort f2bf(float f) {
    union { float f; unsigned u; } x; x.f = f;
    unsigned r = x.u + 0x7fffu + ((x.u >> 16) & 1u);   // RNE
    return (ushort)(r >> 16);
}

__device__ __forceinline__ f32x16 zero16() {
    f32x16 z;
#pragma unroll
    for (int i = 0; i < 16; ++i) z[i] = 0.f;
    return z;
}

// ---------------------------------------------------------------------------
// K0: pack weights fp32 [co][ci][3][3] -> bf16 A-fragment image.
// Image: [dx][s=dy*4+ci16][gp][co][8ci]  (granule = 8 consecutive ci = 16B)
// ---------------------------------------------------------------------------
__global__ void k_prep_w(const float* __restrict__ w, ushort* __restrict__ wimg)
{
    const int e = blockIdx.x * 256 + threadIdx.x;     // 0..36863
    if (e >= 36864) return;
    const int ci07 = e & 7;
    const int co   = (e >> 3) & 63;
    const int gidx = e >> 9;          // 0..71 = dx*24 + s*2 + gp
    const int gp   = gidx & 1;
    const int s    = (gidx >> 1) % 12;
    const int dx   = gidx / 24;
    const int dy   = s >> 2;
    const int ci   = (s & 3) * 16 + gp * 8 + ci07;
    wimg[e] = f2bf(w[((co * 64 + ci) * 3 + dy) * 3 + dx]);
}

// ---------------------------------------------------------------------------
// K1: implicit-GEMM conv3x3 (bf16 MFMA) + LIF + new_pre + new_post.
// Block: 4 waves, (b, 4-row strip). Wave w: co-half = w>>1, x-half = w&1,
// computes 32co x 32x for all 4 rows via v_mfma_f32_32x32x16_bf16.
// A-fragments read directly from global wimg (L2-resident, 73.7 KB).
// LDS: in_lds[6 rows][66 n][64 ci] bf16, 16B-granule XOR-swizzled by n&7.
// 49.5 KB LDS -> 3 blocks/CU.  NO atomics (R4 lesson: 64-way same-address
// atomicAdd contention stalled the kernel to 351 us).
// ---------------------------------------------------------------------------
__global__ __launch_bounds__(256, 3) void k_conv_lif(
    const float* __restrict__ xin, const ushort* __restrict__ wimg,
    const float* __restrict__ membrane, const float* __restrict__ thresh,
    const float* __restrict__ tpre, const float* __restrict__ tpost,
    float* __restrict__ o_spk, float* __restrict__ o_mem, float* __restrict__ o_th,
    float* __restrict__ o_pre, float* __restrict__ o_post)
{
    __shared__ __align__(16) short in_lds[6 * 66 * 64];   // 50688 B

    const int tid = threadIdx.x;
    const int b   = blockIdx.x >> 4;
    const int y0  = (blockIdx.x & 15) << 2;

    // ---- stage input strip rows y0-1..y0+4 (bf16, swizzled) + fused new_pre ----
    for (int it = tid; it < 3168; it += 256) {            // 6r * 8g * 66n
        const int n  = it % 66;
        const int t2 = it / 66;
        const int g  = t2 & 7;
        const int r  = t2 >> 3;
        const int gx = n - 1;
        const int gy = y0 + r - 1;
        const bool inb = ((unsigned)gx < 64u) && ((unsigned)gy < 64u);
        const int base = ((b * 64 + g * 8) * 64 + gy) * 64 + gx;
        float v[8];
#pragma unroll
        for (int j = 0; j < 8; ++j) {
            float f = 0.f;
            if (inb) f = xin[base + j * 4096];
            v[j] = f;
        }
        bf16x8 hv;
#pragma unroll
        for (int j = 0; j < 8; ++j) hv[j] = (short)f2bf(v[j]);
        *(bf16x8*)&in_lds[(r * 66 + n) * 64 + ((g ^ (n & 7)) << 3)] = hv;
        if (r >= 1 && r <= 4 && inb) {                    // rows owned by this block
#pragma unroll
            for (int j = 0; j < 8; ++j) {
                const float q = tpre[base + j * 4096] * 0.95f + v[j];
                o_pre[base + j * 4096] = fminf(fmaxf(q, 0.f), 1.f);
            }
        }
    }
    __syncthreads();

    const int wv = tid >> 6, ln = tid & 63;
    const int ch = wv >> 1, xh = wv & 1;
    const int lh = ln >> 5, l5 = ln & 31;

    f32x16 acc0 = zero16(), acc1 = zero16(), acc2 = zero16(), acc3 = zero16();

    for (int dx = 0; dx < 3; ++dx) {
        const ushort* wp = wimg + dx * 12288;
        const int nsl = xh * 32 + l5 + dx;    // B column slot (0..65)
        const int n7  = nsl & 7;
#pragma unroll
        for (int s = 0; s < 12; ++s) {
            const bf16x8 a = *(const bf16x8*)&wp[(((s * 2 + lh) << 6) + (ch << 5) + l5) * 8];
            const int dy   = s >> 2;
            const int gsw  = (2 * (s & 3) + lh) ^ n7;
            const int boff = (dy * 66 + nsl) * 64 + (gsw << 3);
            acc0 = __builtin_amdgcn_mfma_f32_32x32x16_bf16(
                       a, *(const bf16x8*)&in_lds[boff           ], acc0, 0, 0, 0);
            acc1 = __builtin_amdgcn_mfma_f32_32x32x16_bf16(
                       a, *(const bf16x8*)&in_lds[boff + 1*66*64], acc1, 0, 0, 0);
            acc2 = __builtin_amdgcn_mfma_f32_32x32x16_bf16(
                       a, *(const bf16x8*)&in_lds[boff + 2*66*64], acc2, 0, 0, 0);
            acc3 = __builtin_amdgcn_mfma_f32_32x32x16_bf16(
                       a, *(const bf16x8*)&in_lds[boff + 3*66*64], acc3, 0, 0, 0);
        }
    }

    // ---- LIF epilogue: C/D layout col=lane&31 -> x, row=(r&3)+8*(r>>2)+4*lh -> co
    const int x = xh * 32 + l5;
#define EPILOG(ACC, Y)                                                          \
    {                                                                           \
        const int gy = y0 + (Y);                                                \
        _Pragma("unroll")                                                       \
        for (int rr = 0; rr < 16; ++rr) {                                       \
            const int co  = ch * 32 + (rr & 3) + 8 * (rr >> 2) + 4 * lh;        \
            const int idx = ((b * 64 + co) * 64 + gy) * 64 + x;                 \
            const float mem = membrane[idx] * 0.99f + (ACC)[rr];                \
            const float tv  = thresh[idx];                                      \
            const float sp  = (mem > tv) ? 1.f : 0.f;                           \
            o_spk[idx] = sp;                                                    \
            o_mem[idx] = (sp > 0.f) ? 0.1f : mem;                               \
            o_th[idx]  = (sp > 0.f) ? 1.0f : tv * 0.95f;                        \
            const float q = tpost[idx] * 0.95f + sp;                            \
            o_post[idx] = fminf(fmaxf(q, 0.f), 1.f);                            \
        }                                                                       \
    }
    EPILOG(acc0, 0)
    EPILOG(acc1, 1)
    EPILOG(acc2, 2)
    EPILOG(acc3, 3)
#undef EPILOG
}

// ---------------------------------------------------------------------------
// K2: batch means of new_pre / new_post (float4-vectorized, deep unroll for MLP)
// ---------------------------------------------------------------------------
__global__ void k_avg(const float4* __restrict__ pre, const float4* __restrict__ post,
                      float4* __restrict__ apre, float4* __restrict__ apost)
{
    const int i = blockIdx.x * 256 + threadIdx.x;   // 0..65535 (CHW/4)
    float4 s1 = make_float4(0.f, 0.f, 0.f, 0.f);
    float4 s2 = make_float4(0.f, 0.f, 0.f, 0.f);
#pragma unroll 8
    for (int bb = 0; bb < BB; ++bb) {
        const float4 p = pre[bb * (CHW / 4) + i];
        const float4 q = post[bb * (CHW / 4) + i];
        s1.x += p.x; s1.y += p.y; s1.z += p.z; s1.w += p.w;
        s2.x += q.x; s2.y += q.y; s2.z += q.z; s2.w += q.w;
    }
    const float sc = 1.f / 64.f;
    apre[i]  = make_float4(s1.x * sc, s1.y * sc, s1.z * sc, s1.w * sc);
    apost[i] = make_float4(s2.x * sc, s2.y * sc, s2.z * sc, s2.w * sc);
}

// ---------------------------------------------------------------------------
// K3: delta[c,3,3] = A_POS*corr(avg_post,avg_pre) - A_NEG*corr(avg_post,avg_post)
//     new_w = clip(w + delta, +-0.1). One block per channel.
// ---------------------------------------------------------------------------
__global__ __launch_bounds__(256) void k_wupd(const float* __restrict__ avg_pre,
                                              const float* __restrict__ avg_post,
                                              const float* __restrict__ wgt,
                                              float* __restrict__ o_w)
{
    __shared__ float sp[4096];
    __shared__ float sq[66 * 66];
    __shared__ float sacc[18];
    __shared__ float sdelta[9];
    const int c = blockIdx.x, tid = threadIdx.x;

    for (int t = tid; t < 66 * 66; t += 256) sq[t] = 0.f;
    if (tid < 18) sacc[tid] = 0.f;
    __syncthreads();
    for (int t = tid; t < 4096; t += 256) {
        sp[t] = avg_pre[c * HW + t];
        sq[((t >> 6) + 1) * 66 + (t & 63) + 1] = avg_post[c * HW + t];
    }
    __syncthreads();

    float pot[9] = {0,0,0,0,0,0,0,0,0};
    float dep[9] = {0,0,0,0,0,0,0,0,0};
    for (int t = tid; t < 4096; t += 256) {
        const int yy = t >> 6, xx = t & 63;
        const float p = sp[t];
        const float q = sq[(yy + 1) * 66 + xx + 1];
#pragma unroll
        for (int dy = 0; dy < 3; ++dy)
#pragma unroll
            for (int dxx = 0; dxx < 3; ++dxx) {
                const float v = sq[(yy + dy) * 66 + xx + dxx];
                pot[dy * 3 + dxx] += v * p;
                dep[dy * 3 + dxx] += v * q;
            }
    }
#pragma unroll
    for (int k = 0; k < 18; ++k) {
        float v = (k < 9) ? pot[k] : dep[k - 9];
        for (int off = 32; off > 0; off >>= 1) v += __shfl_down(v, off, 64);
        if ((tid & 63) == 0) atomicAdd(&sacc[k], v);
    }
    __syncthreads();
    if (tid < 9) sdelta[tid] = 0.005f * sacc[tid] - 0.005f * sacc[tid + 9];
    __syncthreads();
    for (int t = tid; t < 576; t += 256) {
        const float v = wgt[c * 576 + t] + sdelta[t % 9];
        o_w[c * 576 + t] = fminf(fmaxf(v, -0.1f), 0.1f);
    }
}

// ---------------------------------------------------------------------------
extern "C" void kernel_launch(void* const* d_in, const int* in_sizes, int n_in,
                              void* d_out, int out_size, void* d_ws, size_t ws_size,
                              hipStream_t stream)
{
    const float* xin   = (const float*)d_in[0];
    const float* wgt   = (const float*)d_in[1];
    const float* mem   = (const float*)d_in[2];
    const float* th    = (const float*)d_in[3];
    const float* tpre  = (const float*)d_in[4];
    const float* tpost = (const float*)d_in[5];

    float* out    = (float*)d_out;
    float* o_spk  = out;
    float* o_mem  = out + (size_t)1 * NTOT;
    float* o_th   = out + (size_t)2 * NTOT;
    float* o_pre  = out + (size_t)3 * NTOT;
    float* o_post = out + (size_t)4 * NTOT;
    float* o_w    = out + (size_t)5 * NTOT;

    ushort* wimg    = (ushort*)d_ws;                       // 36864 ushort = 73728 B
    float* avg_pre  = (float*)((char*)d_ws + 73728);       // 262144 floats
    float* avg_post = avg_pre + CHW;                       // 262144 floats

    hipLaunchKernelGGL(k_prep_w, dim3(144), dim3(256), 0, stream, wgt, wimg);
    hipLaunchKernelGGL(k_conv_lif, dim3(1024), dim3(256), 0, stream,
                       xin, wimg, mem, th, tpre, tpost,
                       o_spk, o_mem, o_th, o_pre, o_post);
    hipLaunchKernelGGL(k_avg, dim3(256), dim3(256), 0, stream,
                       (const float4*)o_pre, (const float4*)o_post,
                       (float4*)avg_pre, (float4*)avg_post);
    hipLaunchKernelGGL(k_wupd, dim3(64), dim3(256), 0, stream,
                       avg_pre, avg_post, wgt, o_w);
}

// Round 13
// 611.657 us; speedup vs baseline: 1.2341x; 1.2341x over previous
//
#include <hip/hip_runtime.h>

typedef __attribute__((ext_vector_type(8))) short bf16x8;
typedef __attribute__((ext_vector_type(16))) float f32x16;

namespace {
constexpr int BB   = 64;
constexpr int CC   = 64;
constexpr int HH   = 64;
constexpr int WW   = 64;
constexpr int HW   = HH * WW;   // 4096
constexpr int CHW  = CC * HW;   // 262144
constexpr int NTOT = BB * CHW;  // 16777216
}

__device__ __forceinline__ ushort f2bf(float f) {
    union { float f; unsigned u; } x; x.f = f;
    unsigned r = x.u + 0x7fffu + ((x.u >> 16) & 1u);   // RNE
    return (ushort)(r >> 16);
}

__device__ __forceinline__ f32x16 zero16() {
    f32x16 z;
#pragma unroll
    for (int i = 0; i < 16; ++i) z[i] = 0.f;
    return z;
}

// ---------------------------------------------------------------------------
// K0: pack weights fp32 [co][ci][3][3] -> bf16 A-fragment image.
// Image: [dx][s=dy*4+ci16][gp][co][8ci]  (granule = 8 consecutive ci = 16B)
// ---------------------------------------------------------------------------
__global__ void k_prep_w(const float* __restrict__ w, ushort* __restrict__ wimg)
{
    const int e = blockIdx.x * 256 + threadIdx.x;     // 0..36863
    if (e >= 36864) return;
    const int ci07 = e & 7;
    const int co   = (e >> 3) & 63;
    const int gidx = e >> 9;          // 0..71 = dx*24 + s*2 + gp
    const int gp   = gidx & 1;
    const int s    = (gidx >> 1) % 12;
    const int dx   = gidx / 24;
    const int dy   = s >> 2;
    const int ci   = (s & 3) * 16 + gp * 8 + ci07;
    wimg[e] = f2bf(w[((co * 64 + ci) * 3 + dy) * 3 + dx]);
}

// ---------------------------------------------------------------------------
// K1: implicit-GEMM conv3x3 (bf16 MFMA) + LIF + new_pre + new_post.
// R10 lesson: A-fragments MUST be LDS-staged (R3 structure, conv <=205us);
// direct global A-reads in the MFMA loop serialize on L2 latency at low
// occupancy (R10: conv 332us, VALUBusy 5%). Reverted to w_lds per-dx slabs,
// launch_bounds(256,2), VGPR 116.  NO avg atomics (R4/R10: -19us only, but
// still avoid device-scope same-address contention).
// ---------------------------------------------------------------------------
__global__ __launch_bounds__(256, 2) void k_conv_lif(
    const float* __restrict__ xin, const ushort* __restrict__ wimg,
    const float* __restrict__ membrane, const float* __restrict__ thresh,
    const float* __restrict__ tpre, const float* __restrict__ tpost,
    float* __restrict__ o_spk, float* __restrict__ o_mem, float* __restrict__ o_th,
    float* __restrict__ o_pre, float* __restrict__ o_post)
{
    __shared__ __align__(16) short in_lds[6 * 66 * 64];   // 50688 B
    __shared__ __align__(16) short w_lds[1536 * 8];       // 24576 B

    const int tid = threadIdx.x;
    const int b   = blockIdx.x >> 4;
    const int y0  = (blockIdx.x & 15) << 2;

    // ---- stage input strip rows y0-1..y0+4 (bf16, swizzled) + fused new_pre ----
    for (int it = tid; it < 3168; it += 256) {            // 6r * 8g * 66n
        const int n  = it % 66;
        const int t2 = it / 66;
        const int g  = t2 & 7;
        const int r  = t2 >> 3;
        const int gx = n - 1;
        const int gy = y0 + r - 1;
        const bool inb = ((unsigned)gx < 64u) && ((unsigned)gy < 64u);
        const int base = ((b * 64 + g * 8) * 64 + gy) * 64 + gx;
        float v[8];
#pragma unroll
        for (int j = 0; j < 8; ++j) {
            float f = 0.f;
            if (inb) f = xin[base + j * 4096];
            v[j] = f;
        }
        bf16x8 hv;
#pragma unroll
        for (int j = 0; j < 8; ++j) hv[j] = (short)f2bf(v[j]);
        *(bf16x8*)&in_lds[(r * 66 + n) * 64 + ((g ^ (n & 7)) << 3)] = hv;
        if (r >= 1 && r <= 4 && inb) {                    // rows owned by this block
#pragma unroll
            for (int j = 0; j < 8; ++j) {
                const float q = tpre[base + j * 4096] * 0.95f + v[j];
                o_pre[base + j * 4096] = fminf(fmaxf(q, 0.f), 1.f);
            }
        }
    }
    // ---- stage W slab dx=0 ----
    for (int i = tid; i < 1536; i += 256)
        *(bf16x8*)&w_lds[i * 8] = *(const bf16x8*)&wimg[i * 8];
    __syncthreads();

    const int wv = tid >> 6, ln = tid & 63;
    const int ch = wv >> 1, xh = wv & 1;
    const int lh = ln >> 5, l5 = ln & 31;

    f32x16 acc0 = zero16(), acc1 = zero16(), acc2 = zero16(), acc3 = zero16();

    for (int dx = 0; dx < 3; ++dx) {
        if (dx) {
            __syncthreads();
            for (int i = tid; i < 1536; i += 256)
                *(bf16x8*)&w_lds[i * 8] = *(const bf16x8*)&wimg[dx * 12288 + i * 8];
            __syncthreads();
        }
        const int nsl = xh * 32 + l5 + dx;    // B column slot (0..65)
        const int n7  = nsl & 7;
#pragma unroll
        for (int s = 0; s < 12; ++s) {
            const bf16x8 a = *(const bf16x8*)&w_lds[(((s * 2 + lh) * 64) + ch * 32 + l5) * 8];
            const int dy   = s >> 2;
            const int gsw  = (2 * (s & 3) + lh) ^ n7;
            const int boff = (dy * 66 + nsl) * 64 + (gsw << 3);
            acc0 = __builtin_amdgcn_mfma_f32_32x32x16_bf16(
                       a, *(const bf16x8*)&in_lds[boff           ], acc0, 0, 0, 0);
            acc1 = __builtin_amdgcn_mfma_f32_32x32x16_bf16(
                       a, *(const bf16x8*)&in_lds[boff + 1*66*64], acc1, 0, 0, 0);
            acc2 = __builtin_amdgcn_mfma_f32_32x32x16_bf16(
                       a, *(const bf16x8*)&in_lds[boff + 2*66*64], acc2, 0, 0, 0);
            acc3 = __builtin_amdgcn_mfma_f32_32x32x16_bf16(
                       a, *(const bf16x8*)&in_lds[boff + 3*66*64], acc3, 0, 0, 0);
        }
    }

    // ---- LIF epilogue: C/D layout col=lane&31 -> x, row=(r&3)+8*(r>>2)+4*lh -> co
    const int x = xh * 32 + l5;
#define EPILOG(ACC, Y)                                                          \
    {                                                                           \
        const int gy = y0 + (Y);                                                \
        _Pragma("unroll")                                                       \
        for (int rr = 0; rr < 16; ++rr) {                                       \
            const int co  = ch * 32 + (rr & 3) + 8 * (rr >> 2) + 4 * lh;        \
            const int idx = ((b * 64 + co) * 64 + gy) * 64 + x;                 \
            const float mem = membrane[idx] * 0.99f + (ACC)[rr];                \
            const float tv  = thresh[idx];                                      \
            const float sp  = (mem > tv) ? 1.f : 0.f;                           \
            o_spk[idx] = sp;                                                    \
            o_mem[idx] = (sp > 0.f) ? 0.1f : mem;                               \
            o_th[idx]  = (sp > 0.f) ? 1.0f : tv * 0.95f;                        \
            const float q = tpost[idx] * 0.95f + sp;                            \
            o_post[idx] = fminf(fmaxf(q, 0.f), 1.f);                            \
        }                                                                       \
    }
    EPILOG(acc0, 0)
    EPILOG(acc1, 1)
    EPILOG(acc2, 2)
    EPILOG(acc3, 3)
#undef EPILOG
}

// ---------------------------------------------------------------------------
// K2: batch means of new_pre / new_post (float4-vectorized, deep unroll for MLP)
// ---------------------------------------------------------------------------
__global__ void k_avg(const float4* __restrict__ pre, const float4* __restrict__ post,
                      float4* __restrict__ apre, float4* __restrict__ apost)
{
    const int i = blockIdx.x * 256 + threadIdx.x;   // 0..65535 (CHW/4)
    float4 s1 = make_float4(0.f, 0.f, 0.f, 0.f);
    float4 s2 = make_float4(0.f, 0.f, 0.f, 0.f);
#pragma unroll 8
    for (int bb = 0; bb < BB; ++bb) {
        const float4 p = pre[bb * (CHW / 4) + i];
        const float4 q = post[bb * (CHW / 4) + i];
        s1.x += p.x; s1.y += p.y; s1.z += p.z; s1.w += p.w;
        s2.x += q.x; s2.y += q.y; s2.z += q.z; s2.w += q.w;
    }
    const float sc = 1.f / 64.f;
    apre[i]  = make_float4(s1.x * sc, s1.y * sc, s1.z * sc, s1.w * sc);
    apost[i] = make_float4(s2.x * sc, s2.y * sc, s2.z * sc, s2.w * sc);
}

// ---------------------------------------------------------------------------
// K3: delta[c,3,3] = A_POS*corr(avg_post,avg_pre) - A_NEG*corr(avg_post,avg_post)
//     new_w = clip(w + delta, +-0.1). One block per channel.
// ---------------------------------------------------------------------------
__global__ __launch_bounds__(256) void k_wupd(const float* __restrict__ avg_pre,
                                              const float* __restrict__ avg_post,
                                              const float* __restrict__ wgt,
                                              float* __restrict__ o_w)
{
    __shared__ float sp[4096];
    __shared__ float sq[66 * 66];
    __shared__ float sacc[18];
    __shared__ float sdelta[9];
    const int c = blockIdx.x, tid = threadIdx.x;

    for (int t = tid; t < 66 * 66; t += 256) sq[t] = 0.f;
    if (tid < 18) sacc[tid] = 0.f;
    __syncthreads();
    for (int t = tid; t < 4096; t += 256) {
        sp[t] = avg_pre[c * HW + t];
        sq[((t >> 6) + 1) * 66 + (t & 63) + 1] = avg_post[c * HW + t];
    }
    __syncthreads();

    float pot[9] = {0,0,0,0,0,0,0,0,0};
    float dep[9] = {0,0,0,0,0,0,0,0,0};
    for (int t = tid; t < 4096; t += 256) {
        const int yy = t >> 6, xx = t & 63;
        const float p = sp[t];
        const float q = sq[(yy + 1) * 66 + xx + 1];
#pragma unroll
        for (int dy = 0; dy < 3; ++dy)
#pragma unroll
            for (int dxx = 0; dxx < 3; ++dxx) {
                const float v = sq[(yy + dy) * 66 + xx + dxx];
                pot[dy * 3 + dxx] += v * p;
                dep[dy * 3 + dxx] += v * q;
            }
    }
#pragma unroll
    for (int k = 0; k < 18; ++k) {
        float v = (k < 9) ? pot[k] : dep[k - 9];
        for (int off = 32; off > 0; off >>= 1) v += __shfl_down(v, off, 64);
        if ((tid & 63) == 0) atomicAdd(&sacc[k], v);
    }
    __syncthreads();
    if (tid < 9) sdelta[tid] = 0.005f * sacc[tid] - 0.005f * sacc[tid + 9];
    __syncthreads();
    for (int t = tid; t < 576; t += 256) {
        const float v = wgt[c * 576 + t] + sdelta[t % 9];
        o_w[c * 576 + t] = fminf(fmaxf(v, -0.1f), 0.1f);
    }
}

// ---------------------------------------------------------------------------
extern "C" void kernel_launch(void* const* d_in, const int* in_sizes, int n_in,
                              void* d_out, int out_size, void* d_ws, size_t ws_size,
                              hipStream_t stream)
{
    const float* xin   = (const float*)d_in[0];
    const float* wgt   = (const float*)d_in[1];
    const float* mem   = (const float*)d_in[2];
    const float* th    = (const float*)d_in[3];
    const float* tpre  = (const float*)d_in[4];
    const float* tpost = (const float*)d_in[5];

    float* out    = (float*)d_out;
    float* o_spk  = out;
    float* o_mem  = out + (size_t)1 * NTOT;
    float* o_th   = out + (size_t)2 * NTOT;
    float* o_pre  = out + (size_t)3 * NTOT;
    float* o_post = out + (size_t)4 * NTOT;
    float* o_w    = out + (size_t)5 * NTOT;

    ushort* wimg    = (ushort*)d_ws;                       // 36864 ushort = 73728 B
    float* avg_pre  = (float*)((char*)d_ws + 73728);       // 262144 floats
    float* avg_post = avg_pre + CHW;                       // 262144 floats

    hipLaunchKernelGGL(k_prep_w, dim3(144), dim3(256), 0, stream, wgt, wimg);
    hipLaunchKernelGGL(k_conv_lif, dim3(1024), dim3(256), 0, stream,
                       xin, wimg, mem, th, tpre, tpost,
                       o_spk, o_mem, o_th, o_pre, o_post);
    hipLaunchKernelGGL(k_avg, dim3(256), dim3(256), 0, stream,
                       (const float4*)o_pre, (const float4*)o_post,
                       (float4*)avg_pre, (float4*)avg_post);
    hipLaunchKernelGGL(k_wupd, dim3(64), dim3(256), 0, stream,
                       avg_pre, avg_post, wgt, o_w);
}